// Round 1
// baseline (1279.479 us; speedup 1.0000x reference)
//
#include <hip/hip_runtime.h>
#include <math.h>

#define NNODES 10000
#define NT     80000
#define NE     1280000

__device__ __forceinline__ float sigm(float x){ return 1.0f/(1.0f+expf(-x)); }

// Build combined LSTM weight/bias buffers:
// W1c [256][192] = [wih1 | whh1] rows, W2c [256][128] = [wih2 | whh2] rows
__global__ __launch_bounds__(256) void prep_w_kernel(
    const float* __restrict__ wih1, const float* __restrict__ whh1,
    const float* __restrict__ bih1, const float* __restrict__ bhh1,
    const float* __restrict__ wih2, const float* __restrict__ whh2,
    const float* __restrict__ bih2, const float* __restrict__ bhh2,
    float* __restrict__ W1c, float* __restrict__ W2c,
    float* __restrict__ bs1, float* __restrict__ bs2)
{
    int gid = blockIdx.x*256 + threadIdx.x;
    if (gid < 256*192) {
        int j = gid/192, k = gid%192;
        W1c[gid] = (k < 128) ? wih1[j*128 + k] : whh1[j*64 + (k-128)];
    } else if (gid < 256*192 + 256*128) {
        int r = gid - 256*192; int j = r/128, k = r%128;
        W2c[r] = (k < 64) ? wih2[j*64 + k] : whh2[j*64 + (k-64)];
    } else if (gid < 256*192 + 256*128 + 256) {
        int j = gid - (256*192 + 256*128); bs1[j] = bih1[j] + bhh1[j];
    } else if (gid < 256*192 + 256*128 + 512) {
        int j = gid - (256*192 + 256*128 + 256); bs2[j] = bih2[j] + bhh2[j];
    }
}

__global__ __launch_bounds__(256) void deg_kernel(const int* __restrict__ dst,
                                                  const float* __restrict__ ew,
                                                  float* __restrict__ deg)
{
    int gid = blockIdx.x*blockDim.x + threadIdx.x;
    int stride = gridDim.x*blockDim.x;
    for (int e = gid; e < NE; e += stride)
        atomicAdd(&deg[dst[e]], ew[e]);
}

__global__ __launch_bounds__(256) void dinv_kernel(float* __restrict__ deg)
{
    int gid = blockIdx.x*256 + threadIdx.x;
    if (gid < NT) deg[gid] = rsqrtf(deg[gid] + 1.0f);
}

// h[n][j] = sum_k X[n][k] * w[k][j], K=8
__global__ __launch_bounds__(256) void gemm8_kernel(const float* __restrict__ X,
                                                    const float* __restrict__ w,
                                                    float* __restrict__ h)
{
    __shared__ float ws[512];
    for (int i = threadIdx.x; i < 512; i += 256) ws[i] = w[i];
    __syncthreads();
    int gid = blockIdx.x*256 + threadIdx.x;
    int n = gid >> 6, j = gid & 63;
    const float* xr = X + (size_t)n*8;
    float a = 0.f;
    #pragma unroll
    for (int k = 0; k < 8; ++k) a = fmaf(xr[k], ws[k*64 + j], a);
    h[gid] = a;
}

// h[n][j] = sum_k x[n][k] * w[k][j], K=64
__global__ __launch_bounds__(256) void gemm64_kernel(const float* __restrict__ x,
                                                     const float* __restrict__ w,
                                                     float* __restrict__ h)
{
    __shared__ float ws[4096];
    for (int i = threadIdx.x; i < 4096; i += 256) ws[i] = w[i];
    __syncthreads();
    int gid = blockIdx.x*256 + threadIdx.x;
    int n = gid >> 6, j = gid & 63;
    const float4* xr = (const float4*)(x + (size_t)n*64);
    float a = 0.f;
    #pragma unroll
    for (int kk = 0; kk < 16; ++kk) {
        float4 xv = xr[kk];
        a = fmaf(xv.x, ws[(kk*4+0)*64 + j], a);
        a = fmaf(xv.y, ws[(kk*4+1)*64 + j], a);
        a = fmaf(xv.z, ws[(kk*4+2)*64 + j], a);
        a = fmaf(xv.w, ws[(kk*4+3)*64 + j], a);
    }
    h[gid] = a;
}

// one wave per edge: lane = channel; agg[dst] += norm * h[src]
__global__ __launch_bounds__(256) void scatter_kernel(const int* __restrict__ src,
                                                      const int* __restrict__ dst,
                                                      const float* __restrict__ ew,
                                                      const float* __restrict__ dinv,
                                                      const float* __restrict__ h,
                                                      float* __restrict__ agg)
{
    int lane = threadIdx.x & 63;
    int wid = (blockIdx.x*blockDim.x + threadIdx.x) >> 6;
    int nw  = (gridDim.x*blockDim.x) >> 6;
    for (int e = wid; e < NE; e += nw) {
        int s = src[e], d = dst[e];
        float wgt = ew[e] * dinv[s] * dinv[d];
        atomicAdd(&agg[(size_t)d*64 + lane], wgt * h[(size_t)s*64 + lane]);
    }
}

// y = relu(agg + h*dinv^2 + b) in place; accumulate per-channel sum/sumsq
__global__ __launch_bounds__(256) void gcnpost_kernel(float* __restrict__ y,
                                                      const float* __restrict__ h,
                                                      const float* __restrict__ dinv,
                                                      const float* __restrict__ b,
                                                      float* __restrict__ sums)
{
    int c = threadIdx.x & 63, w = threadIdx.x >> 6;
    float bc = b[c];
    float s = 0.f, q = 0.f;
    for (int r = blockIdx.x*4 + w; r < NT; r += gridDim.x*4) {
        float dv = dinv[r];
        float v = y[(size_t)r*64 + c] + h[(size_t)r*64 + c]*dv*dv + bc;
        v = fmaxf(v, 0.f);
        y[(size_t)r*64 + c] = v;
        s += v; q += v*v;
    }
    __shared__ float sm[256], sq[256];
    sm[threadIdx.x] = s; sq[threadIdx.x] = q;
    __syncthreads();
    if (threadIdx.x < 64) {
        float ts = sm[c] + sm[c+64] + sm[c+128] + sm[c+192];
        float tq = sq[c] + sq[c+64] + sq[c+128] + sq[c+192];
        atomicAdd(&sums[c], ts);
        atomicAdd(&sums[64 + c], tq);
    }
}

__global__ __launch_bounds__(256) void bnapply_kernel(const float* __restrict__ y,
                                                      float* __restrict__ xo,
                                                      const float* __restrict__ sums,
                                                      const float* __restrict__ g,
                                                      const float* __restrict__ be)
{
    int gid = blockIdx.x*256 + threadIdx.x;
    int c = gid & 63;
    float mu  = sums[c] * (1.0f/NT);
    float var = sums[64 + c] * (1.0f/NT) - mu*mu;
    xo[gid] = (y[gid] - mu) * rsqrtf(var + 1e-5f) * g[c] + be[c];
}

// Fused 2-layer, 8-step LSTM. Block = 256 threads, 16 nodes.
// Thread t owns gate-row j=t (of 256) for all 16 nodes; z exchanged via LDS.
#define NB 16
__global__ __launch_bounds__(256) void lstm_kernel(const float* __restrict__ x1,
                                                   const float* __restrict__ x2,
                                                   const float* __restrict__ W1c,
                                                   const float* __restrict__ W2c,
                                                   const float* __restrict__ bs1,
                                                   const float* __restrict__ bs2,
                                                   float* __restrict__ out)
{
    __shared__ __align__(16) float xA[NB][192];  // [x1_t | x2_t | h1_prev]
    __shared__ __align__(16) float xB[NB][128];  // [h1_t | h2_prev]
    __shared__ float zb[NB][256];
    int t = threadIdx.x;
    int nb0 = blockIdx.x * NB;
    for (int i = t; i < NB*64;  i += 256) xA[i>>6][128 + (i&63)] = 0.f;
    for (int i = t; i < NB*128; i += 256) xB[i>>7][i & 127] = 0.f;
    float c1[4], c2[4], h1v[4], h2v[4];
    #pragma unroll
    for (int r = 0; r < 4; ++r) { c1[r] = 0.f; c2[r] = 0.f; }
    __syncthreads();

    const float4* w1r = (const float4*)(W1c + (size_t)t*192);
    const float4* w2r = (const float4*)(W2c + (size_t)t*128);
    float b1v = bs1[t], b2v = bs2[t];

    for (int step = 0; step < 8; ++step) {
        // stage this timestep's GCN features
        for (int i = t; i < NB*128; i += 256) {
            int n = i >> 7, k = i & 127;
            size_t row = (size_t)(step*NNODES + nb0 + n);
            xA[n][k] = (k < 64) ? x1[row*64 + k] : x2[row*64 + (k-64)];
        }
        __syncthreads();

        // layer-1 gate pre-activations
        float acc[NB];
        #pragma unroll
        for (int n = 0; n < NB; ++n) acc[n] = b1v;
        for (int kk = 0; kk < 48; ++kk) {
            float4 w = w1r[kk];
            #pragma unroll
            for (int n = 0; n < NB; ++n) {
                float4 xv = *(const float4*)&xA[n][kk*4];
                acc[n] = fmaf(w.x, xv.x, acc[n]);
                acc[n] = fmaf(w.y, xv.y, acc[n]);
                acc[n] = fmaf(w.z, xv.z, acc[n]);
                acc[n] = fmaf(w.w, xv.w, acc[n]);
            }
        }
        #pragma unroll
        for (int n = 0; n < NB; ++n) zb[n][t] = acc[n];
        __syncthreads();

        // layer-1 cell/hidden update (thread handles 4 (node,hidden) items)
        #pragma unroll
        for (int r = 0; r < 4; ++r) {
            int item = t + 256*r;
            int n = item >> 6, l = item & 63;
            float zi = zb[n][l], zf = zb[n][64+l], zg = zb[n][128+l], zo = zb[n][192+l];
            float c = sigm(zf)*c1[r] + sigm(zi)*tanhf(zg);
            c1[r] = c;
            h1v[r] = sigm(zo)*tanhf(c);
            xB[n][l]       = h1v[r];
            xA[n][128 + l] = h1v[r];
        }
        __syncthreads();

        // layer-2 gate pre-activations
        #pragma unroll
        for (int n = 0; n < NB; ++n) acc[n] = b2v;
        for (int kk = 0; kk < 32; ++kk) {
            float4 w = w2r[kk];
            #pragma unroll
            for (int n = 0; n < NB; ++n) {
                float4 xv = *(const float4*)&xB[n][kk*4];
                acc[n] = fmaf(w.x, xv.x, acc[n]);
                acc[n] = fmaf(w.y, xv.y, acc[n]);
                acc[n] = fmaf(w.z, xv.z, acc[n]);
                acc[n] = fmaf(w.w, xv.w, acc[n]);
            }
        }
        #pragma unroll
        for (int n = 0; n < NB; ++n) zb[n][t] = acc[n];
        __syncthreads();

        // layer-2 cell/hidden update
        #pragma unroll
        for (int r = 0; r < 4; ++r) {
            int item = t + 256*r;
            int n = item >> 6, l = item & 63;
            float zi = zb[n][l], zf = zb[n][64+l], zg = zb[n][128+l], zo = zb[n][192+l];
            float c = sigm(zf)*c2[r] + sigm(zi)*tanhf(zg);
            c2[r] = c;
            h2v[r] = sigm(zo)*tanhf(c);
        }
        __syncthreads();
        #pragma unroll
        for (int r = 0; r < 4; ++r) {
            int item = t + 256*r;
            int n = item >> 6, l = item & 63;
            xB[n][64 + l] = h2v[r];
        }
        if (step == 7) {
            #pragma unroll
            for (int r = 0; r < 4; ++r) {
                int item = t + 256*r;
                int n = item >> 6, l = item & 63;
                int node = nb0 + n;
                out[(size_t)node*143 + l]      = h1v[r];
                out[(size_t)node*143 + 64 + l] = h2v[r];
            }
        }
        __syncthreads();
    }
}

__global__ __launch_bounds__(256) void sfeat_kernel(const float* __restrict__ X,
                                                    float* __restrict__ out)
{
    int gid = blockIdx.x*256 + threadIdx.x;
    if (gid >= NNODES*15) return;
    int n = gid/15, i = gid%15;
    float v = (i < 8) ? X[(size_t)n*8 + i]
                      : X[((size_t)(i-7)*NNODES + n)*8 + 7];
    out[(size_t)n*143 + 128 + i] = v;
}

extern "C" void kernel_launch(void* const* d_in, const int* in_sizes, int n_in,
                              void* d_out, int out_size, void* d_ws, size_t ws_size,
                              hipStream_t stream)
{
    (void)in_sizes; (void)n_in; (void)out_size; (void)ws_size;
    const float* X    = (const float*)d_in[0];
    const int*   ei   = (const int*)d_in[1];
    const float* ew   = (const float*)d_in[2];
    const float* w1   = (const float*)d_in[3];
    const float* b1   = (const float*)d_in[4];
    const float* w2   = (const float*)d_in[5];
    const float* b2   = (const float*)d_in[6];
    const float* g1   = (const float*)d_in[7];
    const float* be1  = (const float*)d_in[8];
    const float* g2   = (const float*)d_in[9];
    const float* be2  = (const float*)d_in[10];
    const float* wih1 = (const float*)d_in[11];
    const float* whh1 = (const float*)d_in[12];
    const float* bih1 = (const float*)d_in[13];
    const float* bhh1 = (const float*)d_in[14];
    const float* wih2 = (const float*)d_in[15];
    const float* whh2 = (const float*)d_in[16];
    const float* bih2 = (const float*)d_in[17];
    const float* bhh2 = (const float*)d_in[18];
    float* out = (float*)d_out;
    float* ws  = (float*)d_ws;

    const int* src = ei;
    const int* dst = ei + NE;

    // workspace layout (float offsets)
    float* deg  = ws;                          // 80000  (becomes dinv in place)
    float* sums = ws + 80000;                  // 256
    float* agg  = ws + 80256;                  // NT*64 (reused for both layers)
    float* h    = agg + (size_t)NT*64;         // NT*64
    float* x1   = h   + (size_t)NT*64;         // NT*64
    float* x2b  = x1  + (size_t)NT*64;         // NT*64
    float* W1c  = x2b + (size_t)NT*64;         // 49152
    float* W2c  = W1c + 49152;                 // 32768
    float* bs1  = W2c + 32768;                 // 256
    float* bs2  = bs1 + 256;                   // 256

    // zero deg + sums + agg
    hipMemsetAsync(ws, 0, (size_t)(80256 + (size_t)NT*64) * 4, stream);

    prep_w_kernel<<<(82432+255)/256, 256, 0, stream>>>(wih1,whh1,bih1,bhh1,
                                                       wih2,whh2,bih2,bhh2,
                                                       W1c,W2c,bs1,bs2);
    deg_kernel<<<1024, 256, 0, stream>>>(dst, ew, deg);
    dinv_kernel<<<(NT+255)/256, 256, 0, stream>>>(deg);

    // GCN layer 1
    gemm8_kernel<<<NT*64/256, 256, 0, stream>>>(X, w1, h);
    scatter_kernel<<<2048, 256, 0, stream>>>(src, dst, ew, deg, h, agg);
    gcnpost_kernel<<<1024, 256, 0, stream>>>(agg, h, deg, b1, sums);
    bnapply_kernel<<<NT*64/256, 256, 0, stream>>>(agg, x1, sums, g1, be1);

    // GCN layer 2 (re-zero agg)
    hipMemsetAsync(agg, 0, (size_t)NT*64*4, stream);
    gemm64_kernel<<<NT*64/256, 256, 0, stream>>>(x1, w2, h);
    scatter_kernel<<<2048, 256, 0, stream>>>(src, dst, ew, deg, h, agg);
    gcnpost_kernel<<<1024, 256, 0, stream>>>(agg, h, deg, b2, sums + 128);
    bnapply_kernel<<<NT*64/256, 256, 0, stream>>>(agg, x2b, sums + 128, g2, be2);

    // fused 2-layer LSTM over 8 steps + outputs
    lstm_kernel<<<NNODES/NB, 256, 0, stream>>>(x1, x2b, W1c, W2c, bs1, bs2, out);
    sfeat_kernel<<<(NNODES*15+255)/256, 256, 0, stream>>>(X, out);
}

// Round 2
// 828.571 us; speedup vs baseline: 1.5442x; 1.5442x over previous
//
#include <hip/hip_runtime.h>
#include <hip/hip_bf16.h>
#include <math.h>

#define NNODES 10000
#define NT     80000
#define NE     1280000

typedef __bf16 bf16x8 __attribute__((ext_vector_type(8)));
typedef float  f32x4  __attribute__((ext_vector_type(4)));

__device__ __forceinline__ float frcp(float x){ return __builtin_amdgcn_rcpf(x); }
__device__ __forceinline__ float fsig(float x){ return frcp(1.0f + __expf(-x)); }
__device__ __forceinline__ float ftanh(float x){ return 1.0f - 2.0f*frcp(1.0f + __expf(2.0f*x)); }

// ---------------- weight prep: pack LSTM weights into MFMA B-fragment order ---
// W1f layout: uint32 index = (((w*4+nt)*6+ks)*64 + lane)*4 + i
//   gate = nt*64 + w*16 + (lane&15); k = ks*32 + ((lane>>4)&3)*8 + 2*i (+1 in hi half)
// W2f same with 4 k-slabs.
__global__ __launch_bounds__(256) void prep_w_kernel(
    const float* __restrict__ wih1, const float* __restrict__ whh1,
    const float* __restrict__ bih1, const float* __restrict__ bhh1,
    const float* __restrict__ wih2, const float* __restrict__ whh2,
    const float* __restrict__ bih2, const float* __restrict__ bhh2,
    unsigned int* __restrict__ W1f, unsigned int* __restrict__ W2f,
    float* __restrict__ bs1, float* __restrict__ bs2)
{
    int gid = blockIdx.x*256 + threadIdx.x;
    if (gid < 24576) {
        int i = gid & 3, lane = (gid>>2)&63, rest = gid>>8;
        int ks = rest % 6; rest /= 6;
        int nt = rest & 3, w = rest >> 2;
        int gate = nt*64 + w*16 + (lane & 15);
        int k = ks*32 + ((lane>>4)&3)*8 + 2*i;
        float v0 = (k     < 128) ? wih1[gate*128 + k]       : whh1[gate*64 + (k-128)];
        float v1 = (k + 1 < 128) ? wih1[gate*128 + k + 1]   : whh1[gate*64 + (k+1-128)];
        __hip_bfloat16 h0 = __float2bfloat16(v0), h1 = __float2bfloat16(v1);
        W1f[gid] = (unsigned int)*(unsigned short*)&h0 | ((unsigned int)*(unsigned short*)&h1 << 16);
    } else if (gid < 24576 + 16384) {
        int r = gid - 24576;
        int i = r & 3, lane = (r>>2)&63, rest = r>>8;
        int ks = rest & 3; rest >>= 2;
        int nt = rest & 3, w = rest >> 2;
        int gate = nt*64 + w*16 + (lane & 15);
        int k = ks*32 + ((lane>>4)&3)*8 + 2*i;
        float v0 = (k     < 64) ? wih2[gate*64 + k]     : whh2[gate*64 + (k-64)];
        float v1 = (k + 1 < 64) ? wih2[gate*64 + k + 1] : whh2[gate*64 + (k+1-64)];
        __hip_bfloat16 h0 = __float2bfloat16(v0), h1 = __float2bfloat16(v1);
        W2f[r] = (unsigned int)*(unsigned short*)&h0 | ((unsigned int)*(unsigned short*)&h1 << 16);
    } else if (gid < 24576 + 16384 + 256) {
        int j = gid - (24576 + 16384); bs1[j] = bih1[j] + bhh1[j];
    } else if (gid < 24576 + 16384 + 512) {
        int j = gid - (24576 + 16384 + 256); bs2[j] = bih2[j] + bhh2[j];
    }
}

__global__ __launch_bounds__(256) void deg_kernel(const int* __restrict__ dst,
                                                  const float* __restrict__ ew,
                                                  float* __restrict__ deg)
{
    int gid = blockIdx.x*blockDim.x + threadIdx.x;
    int stride = gridDim.x*blockDim.x;
    for (int e = gid; e < NE; e += stride)
        atomicAdd(&deg[dst[e]], ew[e]);
}

__global__ __launch_bounds__(256) void dinv_kernel(float* __restrict__ deg)
{
    int gid = blockIdx.x*256 + threadIdx.x;
    if (gid < NT) deg[gid] = rsqrtf(deg[gid] + 1.0f);
}

__global__ __launch_bounds__(256) void gemm8_kernel(const float* __restrict__ X,
                                                    const float* __restrict__ w,
                                                    float* __restrict__ h)
{
    __shared__ float ws[512];
    for (int i = threadIdx.x; i < 512; i += 256) ws[i] = w[i];
    __syncthreads();
    int gid = blockIdx.x*256 + threadIdx.x;
    int n = gid >> 6, j = gid & 63;
    const float* xr = X + (size_t)n*8;
    float a = 0.f;
    #pragma unroll
    for (int k = 0; k < 8; ++k) a = fmaf(xr[k], ws[k*64 + j], a);
    h[gid] = a;
}

__global__ __launch_bounds__(256) void gemm64_kernel(const float* __restrict__ x,
                                                     const float* __restrict__ w,
                                                     float* __restrict__ h)
{
    __shared__ float ws[4096];
    for (int i = threadIdx.x; i < 4096; i += 256) ws[i] = w[i];
    __syncthreads();
    int gid = blockIdx.x*256 + threadIdx.x;
    int n = gid >> 6, j = gid & 63;
    const float4* xr = (const float4*)(x + (size_t)n*64);
    float a = 0.f;
    #pragma unroll
    for (int kk = 0; kk < 16; ++kk) {
        float4 xv = xr[kk];
        a = fmaf(xv.x, ws[(kk*4+0)*64 + j], a);
        a = fmaf(xv.y, ws[(kk*4+1)*64 + j], a);
        a = fmaf(xv.z, ws[(kk*4+2)*64 + j], a);
        a = fmaf(xv.w, ws[(kk*4+3)*64 + j], a);
    }
    h[gid] = a;
}

__global__ __launch_bounds__(256) void scatter_kernel(const int* __restrict__ src,
                                                      const int* __restrict__ dst,
                                                      const float* __restrict__ ew,
                                                      const float* __restrict__ dinv,
                                                      const float* __restrict__ h,
                                                      float* __restrict__ agg)
{
    int lane = threadIdx.x & 63;
    int wid = (blockIdx.x*blockDim.x + threadIdx.x) >> 6;
    int nw  = (gridDim.x*blockDim.x) >> 6;
    for (int e = wid; e < NE; e += nw) {
        int s = src[e], d = dst[e];
        float wgt = ew[e] * dinv[s] * dinv[d];
        atomicAdd(&agg[(size_t)d*64 + lane], wgt * h[(size_t)s*64 + lane]);
    }
}

__global__ __launch_bounds__(256) void gcnpost_kernel(float* __restrict__ y,
                                                      const float* __restrict__ h,
                                                      const float* __restrict__ dinv,
                                                      const float* __restrict__ b,
                                                      float* __restrict__ sums)
{
    int c = threadIdx.x & 63, w = threadIdx.x >> 6;
    float bc = b[c];
    float s = 0.f, q = 0.f;
    for (int r = blockIdx.x*4 + w; r < NT; r += gridDim.x*4) {
        float dv = dinv[r];
        float v = y[(size_t)r*64 + c] + h[(size_t)r*64 + c]*dv*dv + bc;
        v = fmaxf(v, 0.f);
        y[(size_t)r*64 + c] = v;
        s += v; q += v*v;
    }
    __shared__ float sm[256], sq[256];
    sm[threadIdx.x] = s; sq[threadIdx.x] = q;
    __syncthreads();
    if (threadIdx.x < 64) {
        float ts = sm[c] + sm[c+64] + sm[c+128] + sm[c+192];
        float tq = sq[c] + sq[c+64] + sq[c+128] + sq[c+192];
        atomicAdd(&sums[c], ts);
        atomicAdd(&sums[64 + c], tq);
    }
}

// BN apply; writes f32 (optional) and bf16 into xcat[node][coloff + c]
__global__ __launch_bounds__(256) void bnapply_kernel(const float* __restrict__ y,
                                                      float* __restrict__ xo,
                                                      unsigned short* __restrict__ xcat,
                                                      int coloff,
                                                      const float* __restrict__ sums,
                                                      const float* __restrict__ g,
                                                      const float* __restrict__ be)
{
    int gid = blockIdx.x*256 + threadIdx.x;
    int c = gid & 63;
    float mu  = sums[c] * (1.0f/NT);
    float var = sums[64 + c] * (1.0f/NT) - mu*mu;
    float v = (y[gid] - mu) * rsqrtf(var + 1e-5f) * g[c] + be[c];
    if (xo) xo[gid] = v;
    __hip_bfloat16 hb = __float2bfloat16(v);
    xcat[(size_t)(gid >> 6)*128 + coloff + c] = *(unsigned short*)&hb;
}

// ---------------- fused 2-layer 8-step LSTM on MFMA --------------------------
// Block: 256 threads (4 waves), 16 nodes. Wave w owns hidden slice [16w,16w+16)
// with gate groups i/f/g/o as the 4 N-tiles (weights pre-reordered).
// LDS xb[16][328] bf16: cols 0:128 = [x1|x2] (staged per step),
// 128:192 = h1, 192:256 = h2. Layer1 A = cols 0:192 (K=192, 6 slabs);
// Layer2 A = cols 128:256 (K=128, 4 slabs). Row stride 656B -> 2-way
// bank aliasing on ds_read_b128 (free).
#define LROW 328
__global__ __launch_bounds__(256, 2) void lstm_mfma_kernel(
    const unsigned short* __restrict__ xcat,
    const unsigned int* __restrict__ W1f, const unsigned int* __restrict__ W2f,
    const float* __restrict__ bs1, const float* __restrict__ bs2,
    float* __restrict__ out)
{
    __shared__ __align__(16) unsigned short xb[16][LROW];
    const int tid  = threadIdx.x;
    const int w    = tid >> 6, lane = tid & 63;
    const int lr   = lane & 15;       // A row (node) / D col (hidden)
    const int lg   = lane >> 4;       // k-group for A/B, row-group for D
    const int nb0  = blockIdx.x * 16;

    // persistent weight fragments (160 VGPRs)
    uint4 w1f[4][6], w2f[4][4];
    {
        const uint4* p1 = (const uint4*)W1f;
        #pragma unroll
        for (int nt = 0; nt < 4; ++nt)
            #pragma unroll
            for (int ks = 0; ks < 6; ++ks)
                w1f[nt][ks] = p1[((w*4 + nt)*6 + ks)*64 + lane];
        const uint4* p2 = (const uint4*)W2f;
        #pragma unroll
        for (int nt = 0; nt < 4; ++nt)
            #pragma unroll
            for (int ks = 0; ks < 4; ++ks)
                w2f[nt][ks] = p2[((w*4 + nt)*4 + ks)*64 + lane];
    }
    float b1v[4], b2v[4];
    #pragma unroll
    for (int nt = 0; nt < 4; ++nt) {
        b1v[nt] = bs1[nt*64 + w*16 + lr];
        b2v[nt] = bs2[nt*64 + w*16 + lr];
    }

    // zero h1/h2 region
    {
        int n = tid >> 4, k0 = 128 + (tid & 15)*8;
        uint4 z; z.x = z.y = z.z = z.w = 0u;
        *(uint4*)&xb[n][k0] = z;
    }
    float c1[4] = {0.f,0.f,0.f,0.f}, c2[4] = {0.f,0.f,0.f,0.f};

    for (int step = 0; step < 8; ++step) {
        // stage this step's [x1|x2] (bf16, pre-converted)
        {
            int n = tid >> 4, k0 = (tid & 15)*8;
            *(uint4*)&xb[n][k0] =
                *(const uint4*)&xcat[((size_t)(step*NNODES + nb0 + n))*128 + k0];
        }
        __syncthreads();

        // ---- layer 1: z = A[16x192] @ W1[192x256] ----
        f32x4 acc[4];
        #pragma unroll
        for (int nt = 0; nt < 4; ++nt) { acc[nt][0]=0.f; acc[nt][1]=0.f; acc[nt][2]=0.f; acc[nt][3]=0.f; }
        #pragma unroll
        for (int ks = 0; ks < 6; ++ks) {
            bf16x8 a = *(const bf16x8*)&xb[lr][ks*32 + lg*8];
            #pragma unroll
            for (int nt = 0; nt < 4; ++nt) {
                union { uint4 u; bf16x8 v; } wb; wb.u = w1f[nt][ks];
                acc[nt] = __builtin_amdgcn_mfma_f32_16x16x32_bf16(a, wb.v, acc[nt], 0, 0, 0);
            }
        }
        __syncthreads();   // all waves' A-reads (incl. h1_prev) done before h1 writes

        #pragma unroll
        for (int r = 0; r < 4; ++r) {
            float zi = acc[0][r] + b1v[0];
            float zf = acc[1][r] + b1v[1];
            float zg = acc[2][r] + b1v[2];
            float zo = acc[3][r] + b1v[3];
            float c  = fsig(zf)*c1[r] + fsig(zi)*ftanh(zg);
            c1[r] = c;
            float hv = fsig(zo)*ftanh(c);
            int node = lg*4 + r;
            __hip_bfloat16 hb = __float2bfloat16(hv);
            xb[node][128 + w*16 + lr] = *(unsigned short*)&hb;
            if (step == 7) out[(size_t)(nb0 + node)*143 + w*16 + lr] = hv;
        }
        __syncthreads();   // h1 visible

        // ---- layer 2: z = A[16x128] @ W2[128x256], A = [h1 | h2_prev] ----
        #pragma unroll
        for (int nt = 0; nt < 4; ++nt) { acc[nt][0]=0.f; acc[nt][1]=0.f; acc[nt][2]=0.f; acc[nt][3]=0.f; }
        #pragma unroll
        for (int ks = 0; ks < 4; ++ks) {
            bf16x8 a = *(const bf16x8*)&xb[lr][128 + ks*32 + lg*8];
            #pragma unroll
            for (int nt = 0; nt < 4; ++nt) {
                union { uint4 u; bf16x8 v; } wb; wb.u = w2f[nt][ks];
                acc[nt] = __builtin_amdgcn_mfma_f32_16x16x32_bf16(a, wb.v, acc[nt], 0, 0, 0);
            }
        }
        __syncthreads();   // all waves' A-reads (incl. h2_prev) done before h2 writes

        #pragma unroll
        for (int r = 0; r < 4; ++r) {
            float zi = acc[0][r] + b2v[0];
            float zf = acc[1][r] + b2v[1];
            float zg = acc[2][r] + b2v[2];
            float zo = acc[3][r] + b2v[3];
            float c  = fsig(zf)*c2[r] + fsig(zi)*ftanh(zg);
            c2[r] = c;
            float hv = fsig(zo)*ftanh(c);
            int node = lg*4 + r;
            __hip_bfloat16 hb = __float2bfloat16(hv);
            xb[node][192 + w*16 + lr] = *(unsigned short*)&hb;
            if (step == 7) out[(size_t)(nb0 + node)*143 + 64 + w*16 + lr] = hv;
        }
        __syncthreads();   // h2 visible before next step's layer-2 reads
    }
}

__global__ __launch_bounds__(256) void sfeat_kernel(const float* __restrict__ X,
                                                    float* __restrict__ out)
{
    int gid = blockIdx.x*256 + threadIdx.x;
    if (gid >= NNODES*15) return;
    int n = gid/15, i = gid%15;
    float v = (i < 8) ? X[(size_t)n*8 + i]
                      : X[((size_t)(i-7)*NNODES + n)*8 + 7];
    out[(size_t)n*143 + 128 + i] = v;
}

extern "C" void kernel_launch(void* const* d_in, const int* in_sizes, int n_in,
                              void* d_out, int out_size, void* d_ws, size_t ws_size,
                              hipStream_t stream)
{
    (void)in_sizes; (void)n_in; (void)out_size; (void)ws_size;
    const float* X    = (const float*)d_in[0];
    const int*   ei   = (const int*)d_in[1];
    const float* ew   = (const float*)d_in[2];
    const float* w1   = (const float*)d_in[3];
    const float* b1   = (const float*)d_in[4];
    const float* w2   = (const float*)d_in[5];
    const float* b2   = (const float*)d_in[6];
    const float* g1   = (const float*)d_in[7];
    const float* be1  = (const float*)d_in[8];
    const float* g2   = (const float*)d_in[9];
    const float* be2  = (const float*)d_in[10];
    const float* wih1 = (const float*)d_in[11];
    const float* whh1 = (const float*)d_in[12];
    const float* bih1 = (const float*)d_in[13];
    const float* bhh1 = (const float*)d_in[14];
    const float* wih2 = (const float*)d_in[15];
    const float* whh2 = (const float*)d_in[16];
    const float* bih2 = (const float*)d_in[17];
    const float* bhh2 = (const float*)d_in[18];
    float* out = (float*)d_out;
    float* ws  = (float*)d_ws;

    const int* src = ei;
    const int* dst = ei + NE;

    // workspace layout
    float* deg  = ws;                                   // 80000 (becomes dinv)
    float* sums = ws + 80000;                           // 256
    float* agg  = ws + 80256;                           // NT*64
    float* h    = agg + (size_t)NT*64;                  // NT*64
    float* x1   = h   + (size_t)NT*64;                  // NT*64
    unsigned short* xcat = (unsigned short*)(x1 + (size_t)NT*64);  // NT*128 bf16
    unsigned int* W1f = (unsigned int*)(xcat + (size_t)NT*128);    // 24576
    unsigned int* W2f = W1f + 24576;                    // 16384
    float* bs1 = (float*)(W2f + 16384);                 // 256
    float* bs2 = bs1 + 256;                             // 256

    hipMemsetAsync(ws, 0, (size_t)(80256 + (size_t)NT*64) * 4, stream);

    prep_w_kernel<<<162, 256, 0, stream>>>(wih1,whh1,bih1,bhh1,
                                           wih2,whh2,bih2,bhh2,
                                           W1f,W2f,bs1,bs2);
    deg_kernel<<<1024, 256, 0, stream>>>(dst, ew, deg);
    dinv_kernel<<<(NT+255)/256, 256, 0, stream>>>(deg);

    // GCN layer 1
    gemm8_kernel<<<NT*64/256, 256, 0, stream>>>(X, w1, h);
    scatter_kernel<<<2048, 256, 0, stream>>>(src, dst, ew, deg, h, agg);
    gcnpost_kernel<<<1024, 256, 0, stream>>>(agg, h, deg, b1, sums);
    bnapply_kernel<<<NT*64/256, 256, 0, stream>>>(agg, x1, xcat, 0, sums, g1, be1);

    // GCN layer 2
    hipMemsetAsync(agg, 0, (size_t)NT*64*4, stream);
    gemm64_kernel<<<NT*64/256, 256, 0, stream>>>(x1, w2, h);
    scatter_kernel<<<2048, 256, 0, stream>>>(src, dst, ew, deg, h, agg);
    gcnpost_kernel<<<1024, 256, 0, stream>>>(agg, h, deg, b2, sums + 128);
    bnapply_kernel<<<NT*64/256, 256, 0, stream>>>(agg, nullptr, xcat, 64, sums + 128, g2, be2);

    // fused MFMA LSTM
    lstm_mfma_kernel<<<NNODES/16, 256, 0, stream>>>(xcat, W1f, W2f, bs1, bs2, out);
    sfeat_kernel<<<(NNODES*15+255)/256, 256, 0, stream>>>(X, out);
}